// Round 14
// baseline (907.216 us; speedup 1.0000x reference)
//
#include <hip/hip_runtime.h>
#include <stdint.h>

// ---- Problem constants ----
// B=8192, IN=2048, OUT=2048, G=4.  K_total = 4096 (x-half then h-half).
// gates[b][g][o] = sum_k x[b][k]*Wi[g][k][o] + bi[g][o] + sum_k h[b][k]*Wh[g][k][o] + bh[g][o]
// next_c = sig(g1)*prev_c + sig(g0)*sig(g2);  next_h = sig(g3) + tanh(next_c)
// d_out = [next_h (8192*2048 f32)] ++ [next_c (8192*2048 f32)]
//
// Round-14: B-direct-from-global (minimal diff vs r12).
//   Diagnosis: LDS unit ~70% busy (192KB frag reads + 64KB DMA per block-K-tile) vs MFMA
//   pipe ~15% -> LDS-throughput-bound. Fix: bfr producer becomes a global b128 load (B
//   panel L2-resident); stageB removed; B leaves LDS. LDS traffic 256->160 KB/K-tile.
//   r10's failure causes fixed: B loaded ONE PHASE before use (L2 latency hides under
//   MFMAs), and the vmcnt ledger re-derived for the mixed FIFO (stage=2, B-half=4):
//     loop-top [tA0:2, B0G:4]; P1 +B1G+stageA1 (12) -> MQ00 waits B0G = vmcnt(6);
//     P2 MQ01 waits B1G = vmcnt(2); P3 +stageA0' , VMC2 pre-barrier drains tA1 -> barrier
//     proves ALL waves' A staged (r12 race-fix order); P4 primes loadAA+loadB0G. Mirror P5-8.
//   A-frag chain, phase count, live ranges: identical to r12 (r8/r9/r10 lesson: the
//   schedule is a narrow codegen basin — only the bfr producer changed).

#define SZ_ELEMS 16777216
#define HALF_OUT 16777216

typedef __attribute__((ext_vector_type(8))) short bf16x8;
typedef __attribute__((ext_vector_type(4))) float f32x4;
typedef __attribute__((ext_vector_type(8))) unsigned short u16x8;

__device__ __forceinline__ unsigned short f2bf(float f) {
  unsigned int u = __float_as_uint(f);
  u += 0x7FFFu + ((u >> 16) & 1u);   // round-to-nearest-even
  return (unsigned short)(u >> 16);
}

__device__ __forceinline__ void async16(const void* g, void* l) {
  __builtin_amdgcn_global_load_lds(
      (const __attribute__((address_space(1))) void*)g,
      (__attribute__((address_space(3))) void*)l, 16, 0, 0);
}

__device__ __forceinline__ float sigm(float x) { return 1.f / (1.f + __expf(-x)); }

// ---------------- f32 -> bf16 elementwise convert ----------------
__global__ void cvt_bf16_kernel(const float* __restrict__ src,
                                unsigned short* __restrict__ dst, int n4) {
  int i = blockIdx.x * blockDim.x + threadIdx.x;
  int stride = gridDim.x * blockDim.x;
  for (; i < n4; i += stride) {
    float4 v = reinterpret_cast<const float4*>(src)[i];
    ushort4 o;
    o.x = f2bf(v.x); o.y = f2bf(v.y); o.z = f2bf(v.z); o.w = f2bf(v.w);
    reinterpret_cast<ushort4*>(dst)[i] = o;
  }
}

// ---------------- W [g][k][o] f32  ->  Wt [g][o][k] bf16 ----------------
__global__ void transpose_w_kernel(const float* __restrict__ Wi, const float* __restrict__ Wh,
                                   unsigned short* __restrict__ Wit, unsigned short* __restrict__ Wht) {
  __shared__ float tile[64][65];
  const int tk = blockIdx.x, to = blockIdx.y, gz = blockIdx.z;
  const float* W = (gz < 4 ? Wi : Wh) + (size_t)(gz & 3) * 4194304;
  unsigned short* Wt = (gz < 4 ? Wit : Wht) + (size_t)(gz & 3) * 4194304;
  const int t = threadIdx.x;
  const int o = t & 63, kr = t >> 6;
#pragma unroll
  for (int p = 0; p < 16; ++p) {
    int k = p * 4 + kr;
    tile[k][o] = W[(size_t)(tk * 64 + k) * 2048 + to * 64 + o];
  }
  __syncthreads();
#pragma unroll
  for (int p = 0; p < 2; ++p) {
    int idx = p * 256 + t;
    int orow = idx >> 3, k0 = (idx & 7) * 8;
    u16x8 v;
#pragma unroll
    for (int i = 0; i < 8; ++i) v[i] = f2bf(tile[k0 + i][orow]);
    *reinterpret_cast<u16x8*>(&Wt[(size_t)(to * 64 + orow) * 2048 + tk * 64 + k0]) = v;
  }
}

// ---------------- fused GEMM (4 gates) + LSTM epilogue, 8-phase, B-direct ----------------
// BM=256 batch x [4 gates x 64 o], BK=64, 512 threads (8 waves: 2M x 4N).
// A: LDS double-buffered (2 x 32KB), staged via global_load_lds, XOR-swizzled.
// B: direct global->VGPR b128 loads each K-tile (L2-resident panel), no LDS.
#define FENCE asm volatile("" ::: "memory")
#define BARRIER do { FENCE; __builtin_amdgcn_s_barrier(); FENCE; } while (0)
#define VMC2  asm volatile("s_waitcnt vmcnt(2)" ::: "memory")
#define VMC0  asm volatile("s_waitcnt vmcnt(0)" ::: "memory")

__global__ __launch_bounds__(512, 2) void lstm_gemm_kernel(
    const unsigned short* __restrict__ xb, const unsigned short* __restrict__ hb,
    const unsigned short* __restrict__ wit, const unsigned short* __restrict__ wht,
    const float* __restrict__ bi, const float* __restrict__ bh,
    const float* __restrict__ prev_c, float* __restrict__ out) {
  __shared__ char lds[65536];   // 2 x 32KB A buffers only

  const int tid = threadIdx.x;
  const int wave = tid >> 6, lane = tid & 63;
  const int wm = wave >> 2, wn = wave & 3;
  const int bm = blockIdx.x;   // 0..31 (batch tile, inner-fast) — r5-verified mapping
  const int bo = blockIdx.y;   // 0..31 (out-col tile)

  // --- A fragment ds_read offsets (unchanged from r12) ---
  const int kwin = (lane >> 4) << 4;
  const int fswz = (lane & 7) << 4;
  int aro[8];
#pragma unroll
  for (int mf = 0; mf < 8; ++mf) aro[mf] = (wm * 128 + mf * 16 + (lane & 15)) * 128;

  // --- B global fragment offsets: byte = g*8388608 + o*4096 + k*2 within W^T [g][o][k] ---
  int bgo[4][2];
#pragma unroll
  for (int nf = 0; nf < 4; ++nf)
#pragma unroll
    for (int ks = 0; ks < 2; ++ks)
      bgo[nf][ks] = nf * 8388608 + (wn * 16 + (lane & 15)) * 4096 + ks * 64 + kwin;

  // --- A staging offsets (pre-swizzled global src, linear LDS dest; rule #21) ---
  const int L0 = tid * 16;
  int agoff[2][2];
#pragma unroll
  for (int h = 0; h < 2; ++h)
#pragma unroll
    for (int j = 0; j < 2; ++j) {
      int L = j * 8192 + L0;
      int row = h * 128 + (L >> 7);                // 0..255
      agoff[h][j] = row * 4096 + ((L & 127) ^ ((row & 7) << 4));
    }
  const char* pxa = (const char*)xb + (size_t)bm * 1048576;
  const char* pha = (const char*)hb + (size_t)bm * 1048576;
  const char* pwi = (const char*)wit + (size_t)bo * 262144;
  const char* pwh = (const char*)wht + (size_t)bo * 262144;

  auto stageA = [&](int t, int h, int buf) {       // one 16KB A half-tile (2 loads/thread)
    const char* base = (t < 32) ? (pxa + t * 128) : (pha + (t - 32) * 128);
    char* d = lds + buf * 32768 + h * 16384 + L0;
    async16(base + agoff[h][0], d);
    async16(base + agoff[h][1], d + 8192);
  };

  f32x4 acc[8][4];
  const f32x4 zero = {0.f, 0.f, 0.f, 0.f};
#pragma unroll
  for (int mf = 0; mf < 8; ++mf)
#pragma unroll
    for (int nf = 0; nf < 4; ++nf) acc[mf][nf] = zero;

  bf16x8 afrA[4][2];   // A frags, m-half 0 (rows wm*128 + 0..63)
  bf16x8 afrB[4][2];   // A frags, m-half 1 (rows wm*128 + 64..127)
  bf16x8 bfr[4][2];    // B frags (global-loaded registers)

  auto loadAA = [&](int buf) {            // 8 ds_read_b128
    const char* l = lds + buf * 32768;
#pragma unroll
    for (int m = 0; m < 4; ++m)
#pragma unroll
      for (int ks = 0; ks < 2; ++ks)
        afrA[m][ks] = *(const bf16x8*)(l + aro[m] + ((ks * 64 + kwin) ^ fswz));
  };
  auto loadAB = [&](int buf) {            // 8 ds_read_b128
    const char* l = lds + buf * 32768;
#pragma unroll
    for (int m = 0; m < 4; ++m)
#pragma unroll
      for (int ks = 0; ks < 2; ++ks)
        afrB[m][ks] = *(const bf16x8*)(l + aro[4 + m] + ((ks * 64 + kwin) ^ fswz));
  };
  auto loadB0G = [&](int t) {             // 4 global b128 (gates 0,1)
    const char* base = (t < 32) ? (pwi + t * 128) : (pwh + (t - 32) * 128);
#pragma unroll
    for (int n = 0; n < 2; ++n)
#pragma unroll
      for (int ks = 0; ks < 2; ++ks)
        bfr[n][ks] = *(const bf16x8*)(base + bgo[n][ks]);
  };
  auto loadB1G = [&](int t) {             // 4 global b128 (gates 2,3)
    const char* base = (t < 32) ? (pwi + t * 128) : (pwh + (t - 32) * 128);
#pragma unroll
    for (int n = 0; n < 2; ++n)
#pragma unroll
      for (int ks = 0; ks < 2; ++ks)
        bfr[2 + n][ks] = *(const bf16x8*)(base + bgo[2 + n][ks]);
  };
  auto MQ = [&](int mh, int nh) {         // 16 MFMA: quadrant (mh, nh)
    __builtin_amdgcn_s_setprio(1);
#pragma unroll
    for (int ks = 0; ks < 2; ++ks)
#pragma unroll
      for (int n = 0; n < 2; ++n)
#pragma unroll
        for (int m = 0; m < 4; ++m)
          acc[mh * 4 + m][nh * 2 + n] = __builtin_amdgcn_mfma_f32_16x16x32_bf16(
              (mh ? afrB : afrA)[m][ks], bfr[nh * 2 + n][ks],
              acc[mh * 4 + m][nh * 2 + n], 0, 0, 0);
    __builtin_amdgcn_s_setprio(0);
  };

  // --- prologue: A(t0)->buf0, A(t1) first half ->buf1; prime Q00 ---
  stageA(0, 0, 0); stageA(0, 1, 0); stageA(1, 0, 1);   // queue: 6
  VMC2;                 // own t0 A drained (queue: [t1A0:2])
  BARRIER;              // ALL waves' t0 A proven
  loadAA(0); loadB0G(0);  // queue: [t1A0:2, B0G(0):4]  — loop invariant

  // --- main loop: iterations 0..30, tiles t0=2i (buf0), t1=2i+1 (buf1) ---
  for (int i = 0; i < 31; ++i) {
    const int t0 = 2 * i, t1 = 2 * i + 1, t2 = 2 * i + 2, t3 = 2 * i + 3;
    // P1: Q00(t0); B1G(t0) prefetch for P2; stage t1A1
    loadB1G(t0); stageA(t1, 1, 1); MQ(0, 0); BARRIER;   // MQ waits B0G: vmcnt(6)
    // P2: Q01(t0); afrB[buf0] ds prefetch for P3/P4
    MQ(0, 1); loadAB(0); BARRIER;                       // MQ waits B1G: vmcnt(2)
    // P3: Q10(t0); stage t2A0; VMC2 pre-barrier drains t1A1 -> barrier proves ALL t1 A
    stageA(t2, 0, 0); MQ(1, 0); VMC2; BARRIER;
    // P4: Q11(t0); prime Q00(t1): A from buf1 (safe), B0G(t1) global
    MQ(1, 1); loadAA(1); loadB0G(t1); BARRIER;
    // P5: Q00(t1); B1G(t1); stage t2A1
    loadB1G(t1); stageA(t2, 1, 0); MQ(0, 0); BARRIER;
    // P6: Q01(t1); afrB[buf1] prefetch
    MQ(0, 1); loadAB(1); BARRIER;
    // P7: Q10(t1); stage t3A0; VMC2 drains t2A1 -> barrier proves ALL t2 A
    stageA(t3, 0, 1); MQ(1, 0); VMC2; BARRIER;
    // P8: Q11(t1); prime Q00(t2)
    MQ(1, 1); loadAA(0); loadB0G(t2); BARRIER;
  }

  // --- tail: tiles 62 (buf0), 63 (buf1); only stage = t63A1 ---
  loadB1G(62); stageA(63, 1, 1); MQ(0, 0); BARRIER;
  MQ(0, 1); loadAB(0); BARRIER;
  MQ(1, 0); VMC0; BARRIER;                          // t63 A fully landed, proven for all
  MQ(1, 1); loadAA(1); loadB0G(63); BARRIER;
  loadB1G(63); MQ(0, 0); BARRIER;
  MQ(0, 1); loadAB(1); BARRIER;
  MQ(1, 0);
  MQ(1, 1);

  // --- LSTM cell epilogue (lane-local; C/D: col=lane&15, row=(lane>>4)*4+reg) ---
  const int col = lane & 15, rg = lane >> 4;
  const int o = bo * 64 + wn * 16 + col;
  float bs[4];
#pragma unroll
  for (int g = 0; g < 4; ++g) bs[g] = bi[g * 2048 + o] + bh[g * 2048 + o];
#pragma unroll
  for (int mf = 0; mf < 8; ++mf) {
    int bbase = bm * 256 + wm * 128 + mf * 16 + rg * 4;
#pragma unroll
    for (int r = 0; r < 4; ++r) {
      int b = bbase + r;
      float gi = sigm(acc[mf][0][r] + bs[0]);
      float gf = sigm(acc[mf][1][r] + bs[1]);
      float g2 = sigm(acc[mf][2][r] + bs[2]);
      float go = sigm(acc[mf][3][r] + bs[3]);
      float c = prev_c[(size_t)b * 2048 + o];
      float nc = gf * c + gi * g2;
      float e = __expf(2.f * nc);
      float nh = go + (e - 1.f) / (e + 1.f);   // faithful: out_gate + tanh(next_c)
      out[(size_t)b * 2048 + o] = nh;
      out[(size_t)HALF_OUT + (size_t)b * 2048 + o] = nc;
    }
  }
}

extern "C" void kernel_launch(void* const* d_in, const int* in_sizes, int n_in,
                              void* d_out, int out_size, void* d_ws, size_t ws_size,
                              hipStream_t stream) {
  const float* x  = (const float*)d_in[0];
  const float* ph = (const float*)d_in[1];
  const float* pc = (const float*)d_in[2];
  const float* Wi = (const float*)d_in[3];
  const float* Wh = (const float*)d_in[4];
  const float* bi = (const float*)d_in[5];
  const float* bh = (const float*)d_in[6];
  float* out = (float*)d_out;

  if (ws_size < (size_t)4 * SZ_ELEMS * sizeof(unsigned short)) return;
  unsigned short* xb  = (unsigned short*)d_ws;
  unsigned short* hb  = xb + SZ_ELEMS;
  unsigned short* wit = hb + SZ_ELEMS;
  unsigned short* wht = wit + SZ_ELEMS;

  cvt_bf16_kernel<<<2048, 256, 0, stream>>>(x, xb, 4194304);
  cvt_bf16_kernel<<<2048, 256, 0, stream>>>(ph, hb, 4194304);
  transpose_w_kernel<<<dim3(32, 32, 8), 256, 0, stream>>>(Wi, Wh, wit, wht);
  lstm_gemm_kernel<<<dim3(32, 32), 512, 0, stream>>>(xb, hb, wit, wht, bi, bh, pc, out);
}

// Round 15
// 509.816 us; speedup vs baseline: 1.7795x; 1.7795x over previous
//
#include <hip/hip_runtime.h>
#include <stdint.h>

// ---- Problem constants ----
// B=8192, IN=2048, OUT=2048, G=4.  K_total = 4096 (x-half then h-half).
// gates[b][g][o] = sum_k x[b][k]*Wi[g][k][o] + bi[g][o] + sum_k h[b][k]*Wh[g][k][o] + bh[g][o]
// next_c = sig(g1)*prev_c + sig(g0)*sig(g2);  next_h = sig(g3) + tanh(next_c)
// d_out = [next_h (8192*2048 f32)] ++ [next_c (8192*2048 f32)]
//
// Round-15 = round-12 restored byte-for-byte (best verified state):
//   total 511.6 us, GEMM dispatch 465 us (1183 TF = 47% of dense bf16 peak),
//   MfmaUtil 55%, FETCH 430 MB, WRITE 137 MB, zero bank conflicts, deterministic.
// Session evidence: six structural escapes from this schedule all failed —
//   r8 (2-barrier rotation)   -> 1315 us, spill signature
//   r9 (read-hoist)           -> 1015 us, spill signature
//   r10/r14 (B-direct x2)     -> 920/890 us, latency exposure in barrier lockstep
//   r6 (2 blocks/CU)          -> neutral-negative
//   r3/r4 (XCD remaps)        -> FETCH x2.6, neutral time
// The 8-phase + frag-prefetch + race-fixed-vmcnt schedule is a narrow codegen
// basin; the remaining ~25% to an m201-class schedule needs instruction-level
// control unavailable at this source-only loop.

#define SZ_ELEMS 16777216
#define HALF_OUT 16777216

typedef __attribute__((ext_vector_type(8))) short bf16x8;
typedef __attribute__((ext_vector_type(4))) float f32x4;
typedef __attribute__((ext_vector_type(8))) unsigned short u16x8;

__device__ __forceinline__ unsigned short f2bf(float f) {
  unsigned int u = __float_as_uint(f);
  u += 0x7FFFu + ((u >> 16) & 1u);   // round-to-nearest-even
  return (unsigned short)(u >> 16);
}

__device__ __forceinline__ void async16(const void* g, void* l) {
  __builtin_amdgcn_global_load_lds(
      (const __attribute__((address_space(1))) void*)g,
      (__attribute__((address_space(3))) void*)l, 16, 0, 0);
}

__device__ __forceinline__ float sigm(float x) { return 1.f / (1.f + __expf(-x)); }

// ---------------- f32 -> bf16 elementwise convert ----------------
__global__ void cvt_bf16_kernel(const float* __restrict__ src,
                                unsigned short* __restrict__ dst, int n4) {
  int i = blockIdx.x * blockDim.x + threadIdx.x;
  int stride = gridDim.x * blockDim.x;
  for (; i < n4; i += stride) {
    float4 v = reinterpret_cast<const float4*>(src)[i];
    ushort4 o;
    o.x = f2bf(v.x); o.y = f2bf(v.y); o.z = f2bf(v.z); o.w = f2bf(v.w);
    reinterpret_cast<ushort4*>(dst)[i] = o;
  }
}

// ---------------- W [g][k][o] f32  ->  Wt [g][o][k] bf16 ----------------
__global__ void transpose_w_kernel(const float* __restrict__ Wi, const float* __restrict__ Wh,
                                   unsigned short* __restrict__ Wit, unsigned short* __restrict__ Wht) {
  __shared__ float tile[64][65];
  const int tk = blockIdx.x, to = blockIdx.y, gz = blockIdx.z;
  const float* W = (gz < 4 ? Wi : Wh) + (size_t)(gz & 3) * 4194304;
  unsigned short* Wt = (gz < 4 ? Wit : Wht) + (size_t)(gz & 3) * 4194304;
  const int t = threadIdx.x;
  const int o = t & 63, kr = t >> 6;
#pragma unroll
  for (int p = 0; p < 16; ++p) {
    int k = p * 4 + kr;
    tile[k][o] = W[(size_t)(tk * 64 + k) * 2048 + to * 64 + o];
  }
  __syncthreads();
#pragma unroll
  for (int p = 0; p < 2; ++p) {
    int idx = p * 256 + t;
    int orow = idx >> 3, k0 = (idx & 7) * 8;
    u16x8 v;
#pragma unroll
    for (int i = 0; i < 8; ++i) v[i] = f2bf(tile[k0 + i][orow]);
    *reinterpret_cast<u16x8*>(&Wt[(size_t)(to * 64 + orow) * 2048 + tk * 64 + k0]) = v;
  }
}

// ---------------- fused GEMM (4 gates) + LSTM epilogue, 8-phase + frag prefetch ----------
// BM=256 batch x [4 gates x 64 o], BK=64, 512 threads (8 waves: 2M x 4N).
// ONE barrier per phase; each phase's ds_reads are issued at the END of the PREVIOUS phase;
// compiler auto-waitcnt provides counted lgkm before each MFMA.
// Per-wave vmcnt ledger (loads in units of 2 per stage):
//   prologue 14 -> VMC6 drains all t0 (8); loop-top queue = [t1B0,B1,A0] (6)
//   P1 +t1A1(8)  P2 +t2B0(10)  P3 +t2B1(12) VMC4 -> drains t1B0,B1,A0,A1 = ALL t1
//   P4 +t2A0(6)  P5 +t2A1(8)   P6 +t3B0(10) P7 +t3B1(12) VMC4 -> drains ALL t2
//   P8 +t3A0(6)  -> invariant restored.
// Race-fix (r12, verified): VMC4 sits BEFORE the P3/P7 barrier so the barrier proves the
// tile landed for ALL waves before any wave's prime reads in P4/P8 touch it.
#define FENCE asm volatile("" ::: "memory")
#define BARRIER do { FENCE; __builtin_amdgcn_s_barrier(); FENCE; } while (0)
#define VMC6  asm volatile("s_waitcnt vmcnt(6)" ::: "memory")
#define VMC4  asm volatile("s_waitcnt vmcnt(4)" ::: "memory")
#define VMC0  asm volatile("s_waitcnt vmcnt(0)" ::: "memory")

__global__ __launch_bounds__(512, 2) void lstm_gemm_kernel(
    const unsigned short* __restrict__ xb, const unsigned short* __restrict__ hb,
    const unsigned short* __restrict__ wit, const unsigned short* __restrict__ wht,
    const float* __restrict__ bi, const float* __restrict__ bh,
    const float* __restrict__ prev_c, float* __restrict__ out) {
  __shared__ char lds[131072];

  const int tid = threadIdx.x;
  const int wave = tid >> 6, lane = tid & 63;
  const int wm = wave >> 2, wn = wave & 3;
  const int bm = blockIdx.x;   // 0..31 (batch tile, inner-fast) — r5-verified mapping
  const int bo = blockIdx.y;   // 0..31 (out-col tile)

  // --- fragment ds_read offsets ---
  const int kwin = (lane >> 4) << 4;
  const int fswz = (lane & 7) << 4;
  int aro[8], bro[4];
#pragma unroll
  for (int mf = 0; mf < 8; ++mf) aro[mf] = (wm * 128 + mf * 16 + (lane & 15)) * 128;
#pragma unroll
  for (int nf = 0; nf < 4; ++nf) bro[nf] = 32768 + (nf * 64 + wn * 16 + (lane & 15)) * 128;

  // --- staging offsets (pre-swizzled global src, linear LDS dest; rule #21) ---
  const int L0 = tid * 16;
  int agoff[2][2], bgoff[2][2];
#pragma unroll
  for (int h = 0; h < 2; ++h)
#pragma unroll
    for (int j = 0; j < 2; ++j) {
      int L = j * 8192 + L0;
      int row = h * 128 + (L >> 7);                // 0..255
      int c = (L & 127) ^ ((row & 7) << 4);
      agoff[h][j] = row * 4096 + c;                // A row = batch row
      int g = row >> 6, orow = row & 63;           // B row = g*64 + orow
      bgoff[h][j] = g * 8388608 + orow * 4096 + c;
    }
  const char* pxa = (const char*)xb + (size_t)bm * 1048576;
  const char* pha = (const char*)hb + (size_t)bm * 1048576;
  const char* pwi = (const char*)wit + (size_t)bo * 262144;
  const char* pwh = (const char*)wht + (size_t)bo * 262144;

  auto stageA = [&](int t, int h, int buf) {
    const char* base = (t < 32) ? (pxa + t * 128) : (pha + (t - 32) * 128);
    char* d = lds + buf * 65536 + h * 16384 + L0;
    async16(base + agoff[h][0], d);
    async16(base + agoff[h][1], d + 8192);
  };
  auto stageB = [&](int t, int h, int buf) {
    const char* base = (t < 32) ? (pwi + t * 128) : (pwh + (t - 32) * 128);
    char* d = lds + buf * 65536 + 32768 + h * 16384 + L0;
    async16(base + bgoff[h][0], d);
    async16(base + bgoff[h][1], d + 8192);
  };

  f32x4 acc[8][4];
  const f32x4 zero = {0.f, 0.f, 0.f, 0.f};
#pragma unroll
  for (int mf = 0; mf < 8; ++mf)
#pragma unroll
    for (int nf = 0; nf < 4; ++nf) acc[mf][nf] = zero;

  bf16x8 afrA[4][2];   // A frags, m-half 0 (rows wm*128 + 0..63)
  bf16x8 afrB[4][2];   // A frags, m-half 1 (rows wm*128 + 64..127)
  bf16x8 bfr[4][2];    // all 4 gate-fragments live

  auto loadAA = [&](int buf) {            // 8 ds_read_b128
    const char* l = lds + buf * 65536;
#pragma unroll
    for (int m = 0; m < 4; ++m)
#pragma unroll
      for (int ks = 0; ks < 2; ++ks)
        afrA[m][ks] = *(const bf16x8*)(l + aro[m] + ((ks * 64 + kwin) ^ fswz));
  };
  auto loadAB = [&](int buf) {            // 8 ds_read_b128
    const char* l = lds + buf * 65536;
#pragma unroll
    for (int m = 0; m < 4; ++m)
#pragma unroll
      for (int ks = 0; ks < 2; ++ks)
        afrB[m][ks] = *(const bf16x8*)(l + aro[4 + m] + ((ks * 64 + kwin) ^ fswz));
  };
  auto loadB0 = [&](int buf) {            // 4 ds_read_b128 (gates 0,1)
    const char* l = lds + buf * 65536;
#pragma unroll
    for (int n = 0; n < 2; ++n)
#pragma unroll
      for (int ks = 0; ks < 2; ++ks)
        bfr[n][ks] = *(const bf16x8*)(l + bro[n] + ((ks * 64 + kwin) ^ fswz));
  };
  auto loadB1 = [&](int buf) {            // 4 ds_read_b128 (gates 2,3)
    const char* l = lds + buf * 65536;
#pragma unroll
    for (int n = 0; n < 2; ++n)
#pragma unroll
      for (int ks = 0; ks < 2; ++ks)
        bfr[2 + n][ks] = *(const bf16x8*)(l + bro[2 + n] + ((ks * 64 + kwin) ^ fswz));
  };
  auto MQ = [&](int mh, int nh) {         // 16 MFMA: quadrant (mh, nh)
    __builtin_amdgcn_s_setprio(1);
#pragma unroll
    for (int ks = 0; ks < 2; ++ks)
#pragma unroll
      for (int n = 0; n < 2; ++n)
#pragma unroll
        for (int m = 0; m < 4; ++m)
          acc[mh * 4 + m][nh * 2 + n] = __builtin_amdgcn_mfma_f32_16x16x32_bf16(
              (mh ? afrB : afrA)[m][ks], bfr[nh * 2 + n][ks],
              acc[mh * 4 + m][nh * 2 + n], 0, 0, 0);
    __builtin_amdgcn_s_setprio(0);
  };

  // --- prologue: t0 all 4 halves -> buf0; t1 {B0,B1,A0} -> buf1 ---
  stageB(0, 0, 0); stageB(0, 1, 0); stageA(0, 0, 0); stageA(0, 1, 0);
  stageB(1, 0, 1); stageB(1, 1, 1); stageA(1, 0, 1);
  VMC6;                 // own t0 loads drained (queue: t1B0,B1,A0)
  BARRIER;              // -> ALL waves' t0 proven
  loadAA(0); loadB0(0); // Q00(t0) fragments — safe (post-barrier), consumed in P1

  // --- main loop: iterations 0..30, tiles t0=2i (buf0), t1=2i+1 (buf1) ---
  for (int i = 0; i < 31; ++i) {
    const int t1 = 2 * i + 1, t2 = 2 * i + 2, t3 = 2 * i + 3;
    // P1: Q00(t0); prefetch bfr1[buf0]
    stageA(t1, 1, 1); MQ(0, 0); loadB1(0); BARRIER;
    // P2: Q01(t0); prefetch afrB[buf0]
    stageB(t2, 0, 0); MQ(0, 1); loadAB(0); BARRIER;
    // P3: Q10(t0); VMC4 pre-barrier: drains t1A1+older = ALL t1 -> barrier proves it
    stageB(t2, 1, 0); MQ(1, 0); VMC4; BARRIER;
    // P4: Q11(t0); prime Q00(t1) frags (safe: t1 proven at P3 barrier)
    stageA(t2, 0, 0); MQ(1, 1); loadAA(1); loadB0(1); BARRIER;
    // P5: Q00(t1); prefetch bfr1[buf1]
    stageA(t2, 1, 0); MQ(0, 0); loadB1(1); BARRIER;
    // P6: Q01(t1); prefetch afrB[buf1]
    stageB(t3, 0, 1); MQ(0, 1); loadAB(1); BARRIER;
    // P7: Q10(t1); VMC4 pre-barrier: drains ALL t2 -> barrier proves it
    stageB(t3, 1, 1); MQ(1, 0); VMC4; BARRIER;
    // P8: Q11(t1); prime Q00(t2) frags (safe: t2 proven at P7 barrier)
    stageA(t3, 0, 1); MQ(1, 1); loadAA(0); loadB0(0); BARRIER;
  }

  // --- epilogue iteration: tiles 62 (buf0), 63 (buf1); only stage = t63A1 ---
  stageA(63, 1, 1); MQ(0, 0); loadB1(0); BARRIER;
  MQ(0, 1); loadAB(0); BARRIER;
  MQ(1, 0); VMC0; BARRIER;                          // t63 fully landed, proven for all
  MQ(1, 1); loadAA(1); loadB0(1); BARRIER;
  MQ(0, 0); loadB1(1); BARRIER;
  MQ(0, 1); loadAB(1); BARRIER;
  MQ(1, 0); BARRIER;
  MQ(1, 1);

  // --- LSTM cell epilogue (lane-local; C/D: col=lane&15, row=(lane>>4)*4+reg) ---
  const int col = lane & 15, rg = lane >> 4;
  const int o = bo * 64 + wn * 16 + col;
  float bs[4];
#pragma unroll
  for (int g = 0; g < 4; ++g) bs[g] = bi[g * 2048 + o] + bh[g * 2048 + o];
#pragma unroll
  for (int mf = 0; mf < 8; ++mf) {
    int bbase = bm * 256 + wm * 128 + mf * 16 + rg * 4;
#pragma unroll
    for (int r = 0; r < 4; ++r) {
      int b = bbase + r;
      float gi = sigm(acc[mf][0][r] + bs[0]);
      float gf = sigm(acc[mf][1][r] + bs[1]);
      float g2 = sigm(acc[mf][2][r] + bs[2]);
      float go = sigm(acc[mf][3][r] + bs[3]);
      float c = prev_c[(size_t)b * 2048 + o];
      float nc = gf * c + gi * g2;
      float e = __expf(2.f * nc);
      float nh = go + (e - 1.f) / (e + 1.f);   // faithful: out_gate + tanh(next_c)
      out[(size_t)b * 2048 + o] = nh;
      out[(size_t)HALF_OUT + (size_t)b * 2048 + o] = nc;
    }
  }
}

extern "C" void kernel_launch(void* const* d_in, const int* in_sizes, int n_in,
                              void* d_out, int out_size, void* d_ws, size_t ws_size,
                              hipStream_t stream) {
  const float* x  = (const float*)d_in[0];
  const float* ph = (const float*)d_in[1];
  const float* pc = (const float*)d_in[2];
  const float* Wi = (const float*)d_in[3];
  const float* Wh = (const float*)d_in[4];
  const float* bi = (const float*)d_in[5];
  const float* bh = (const float*)d_in[6];
  float* out = (float*)d_out;

  if (ws_size < (size_t)4 * SZ_ELEMS * sizeof(unsigned short)) return;
  unsigned short* xb  = (unsigned short*)d_ws;
  unsigned short* hb  = xb + SZ_ELEMS;
  unsigned short* wit = hb + SZ_ELEMS;
  unsigned short* wht = wit + SZ_ELEMS;

  cvt_bf16_kernel<<<2048, 256, 0, stream>>>(x, xb, 4194304);
  cvt_bf16_kernel<<<2048, 256, 0, stream>>>(ph, hb, 4194304);
  transpose_w_kernel<<<dim3(32, 32, 8), 256, 0, stream>>>(Wi, Wh, wit, wht);
  lstm_gemm_kernel<<<dim3(32, 32), 512, 0, stream>>>(xb, hb, wit, wht, bi, bh, pc, out);
}